// Round 7
// baseline (334.609 us; speedup 1.0000x reference)
//
#include <hip/hip_runtime.h>

// GCN forward on MI355X — R21: XCD-sharded (cache-blocked) gathers.
// R19/R20 diagnosis: agg gathers sit at ~27G line-ops/s, and TCC FETCH_SIZE
// (=L2 fills) for agg128 was 64.5MB vs ~20MB touched -> the 8 non-coherent
// 4MB L2s THRASH on random 128B lines from a 12.8MB working set. The wall is
// the L2-miss path, not a hard L3 limit.
// R21: split source rows into 4 shards (~3.2MB, fits each XCD L2).
//   fill builds per-shard sub-buckets: cnt4[node][4], 24 slots/shard
//   (Poisson(3)/cell -> overflow P~1e-10). agg phase A: persistent f32
//   accumulator per node, SHARD LOOP OUTERMOST -> whole chip gathers from
//   one 3.2MB shard at a time (loose lockstep via co-residency; dispatch
//   boundary = global sync). First touch streams shard into L2s; rest are
//   L2-rate hits. Layer-2 in-loop dinv reads L2-resident cnt4 (int4 sum).
//   5 dispatches + 1 memset:
//     0. memset cnt4
//     1. prep_small: W1/W2/W3 split || zero pp || gcount
//     2. fill_gemm1: sharded edge fill (4/thread) || layer-1 gemm
//     3. agg_gemm<128,1>: sharded gather bufA (inloop dinv) -> gemm W2 -> bufB
//     4. agg_gemm<64,0>:  sharded gather bufB (presum) -> gemm W3 -> bufC
//     5. agg64_pool: gather bufC (presum) -> block reduce -> part. atomics
//     6. pool_head4: fold partitions + FC head
// Predict: agg128 FETCH 64.5->~30MB, dur 43.6->~27us; agg64 similar;
// total 235 -> ~205us. If FETCH drops but dur doesn't: wall is request-rate,
// revert sharding.
// History: R14 258.6. R15 462. R16 277.8. R18 244.8. R19 242.8. R20 235.2.

#define CAP 96    // bucket slots per node total (4 shards x 24)
#define SCAP 24   // slots per (node, shard)
#define NSHARD 4
#define NPART 64  // pooled accumulator partitions

typedef short bf16x8 __attribute__((ext_vector_type(8)));
typedef float f32x4v __attribute__((ext_vector_type(4)));

static inline size_t align256(size_t x) { return (x + 255) & ~(size_t)255; }

__device__ inline unsigned short f2bf_rne(float a) {
    unsigned u = __builtin_bit_cast(unsigned, a);
    u += 0x7fffu + ((u >> 16) & 1u);
    return (unsigned short)(u >> 16);
}
__device__ inline float bf2f(unsigned short h) {
    unsigned u = ((unsigned)h) << 16;
    return __builtin_bit_cast(float, u);
}
__device__ inline f32x4v unpack4(uint2 u) {
    f32x4v r;
    r.x = __builtin_bit_cast(float, u.x << 16);
    r.y = __builtin_bit_cast(float, u.x & 0xffff0000u);
    r.z = __builtin_bit_cast(float, u.y << 16);
    r.w = __builtin_bit_cast(float, u.y & 0xffff0000u);
    return r;
}
__device__ inline uint2 pack4(f32x4v v) {
    uint2 p;
    p.x = (unsigned)f2bf_rne(v.x) | ((unsigned)f2bf_rne(v.y) << 16);
    p.y = (unsigned)f2bf_rne(v.z) | ((unsigned)f2bf_rne(v.w) << 16);
    return p;
}

__device__ inline int lower_bound_i(const int* __restrict__ a, int n, int key) {
    int lo = 0, hi = n;
    while (lo < hi) {
        int mid = (lo + hi) >> 1;
        if (a[mid] < key) lo = mid + 1; else hi = mid;
    }
    return lo;
}

// Dispatch 1 (512 threads): [0,ppb) zero pp; [ppb,ppb+80) W1/W2/W3 split;
// last block computes gcount via binary search on sorted batch.
__global__ __launch_bounds__(512, 4) void prep_small(
        const float* __restrict__ W1, const float* __restrict__ W2,
        const float* __restrict__ W3,
        short* __restrict__ w1h, short* __restrict__ w1l,
        short* __restrict__ w2h, short* __restrict__ w2l,
        short* __restrict__ w3h, short* __restrict__ w3l,
        float* __restrict__ pp, const int* __restrict__ batch,
        int* __restrict__ gcount, int N, int ppb) {
    int b = blockIdx.x;
    int t = threadIdx.x;
    if (b < ppb) {
        pp[b * 512 + t] = 0.f;
        return;
    }
    b -= ppb;
    if (b < 80) {
        const float* W;
        short *wh, *wl;
        int idx, cols;
        if (b < 32)      { W = W1; wh = w1h; wl = w1l; idx = b * 512 + t; cols = 128; }
        else if (b < 64) { W = W2; wh = w2h; wl = w2l; idx = (b - 32) * 512 + t; cols = 128; }
        else             { W = W3; wh = w3h; wl = w3l; idx = (b - 64) * 512 + t; cols = 64; }
        int k = idx / cols, c = idx % cols;
        float a = W[idx];
        unsigned short h = f2bf_rne(a);
        unsigned short l = f2bf_rne(a - bf2f(h));
        wh[c * 128 + k] = (short)h;
        wl[c * 128 + k] = (short)l;
        return;
    }
    if (t < 64) {
        int lo = lower_bound_i(batch, N, t);
        int hi = lower_bound_i(batch, N, t + 1);
        gcount[t] = hi - lo;
    }
}

// Dispatch 2 (512 threads): [0,eb) sharded edge fill (4 chains/thread);
// [eb,...) layer-1 gemm co-resident under the fill's latency.
// fp32 X, 3-product split-bf16 MFMA, UNSCALED bf16 out (dinv in agg128).
__global__ __launch_bounds__(512, 4) void fill_gemm1(
        const int* __restrict__ src, const int* __restrict__ dst, int E, int eb,
        int* __restrict__ cnt4, unsigned short* __restrict__ bucket,
        const float* __restrict__ X, const short* __restrict__ w1h,
        const short* __restrict__ w1l, unsigned short* __restrict__ Gout,
        int N, int shardW) {
    int b = blockIdx.x;
    int t = threadIdx.x;
    if (b < eb) {
        int base = b * 2048;
#pragma unroll
        for (int k = 0; k < 4; ++k) {
            int e = base + k * 512 + t;
            if (e < E) {
                int c = dst[e];
                int srow = src[e];
                int sh = srow / shardW;            // 0..3
                int p = atomicAdd(&cnt4[c * 4 + sh], 1);
                if (p < SCAP)
                    bucket[(size_t)c * CAP + sh * SCAP + p] = (unsigned short)srow;
            }
        }
        return;
    }
    b -= eb;
    // ---- layer-1 gemm: 8 waves, 64x128 tile, CT=2 per wave ----
    __shared__ short Ah[64 * 40], Al[64 * 40];
    __shared__ short Wh[128 * 40], Wl[128 * 40];
    int rowBase = b * 64;
    int wave = t >> 6, lane = t & 63;
    int quad = lane >> 4, l16 = lane & 15;
    int rbase = (wave & 1) * 32;
    int cbase = (wave >> 1) * 32;
    f32x4v acc[2][2];
#pragma unroll
    for (int rt = 0; rt < 2; ++rt)
#pragma unroll
        for (int ct = 0; ct < 2; ++ct) acc[rt][ct] = {0.f, 0.f, 0.f, 0.f};

    for (int ch = 0; ch < 4; ++ch) {
        {
            int r = t >> 3, f4 = t & 7;  // 512 items, one per thread
            int grow = rowBase + r;
            float4 v = make_float4(0.f, 0.f, 0.f, 0.f);
            if (grow < N) v = *(const float4*)(X + (size_t)grow * 128 + ch * 32 + f4 * 4);
            unsigned short h0 = f2bf_rne(v.x), h1 = f2bf_rne(v.y),
                           h2 = f2bf_rne(v.z), h3 = f2bf_rne(v.w);
            unsigned short l0 = f2bf_rne(v.x - bf2f(h0)), l1 = f2bf_rne(v.y - bf2f(h1)),
                           l2 = f2bf_rne(v.z - bf2f(h2)), l3 = f2bf_rne(v.w - bf2f(h3));
            uint2 hp, lp;
            hp.x = (unsigned)h0 | ((unsigned)h1 << 16);
            hp.y = (unsigned)h2 | ((unsigned)h3 << 16);
            lp.x = (unsigned)l0 | ((unsigned)l1 << 16);
            lp.y = (unsigned)l2 | ((unsigned)l3 << 16);
            *(uint2*)&Ah[r * 40 + f4 * 4] = hp;
            *(uint2*)&Al[r * 40 + f4 * 4] = lp;
        }
        {
            int c = t >> 2, seg = t & 3;  // 512 items, one per thread
            *(uint4*)&Wh[c * 40 + seg * 8] =
                *(const uint4*)(w1h + (size_t)c * 128 + ch * 32 + seg * 8);
            *(uint4*)&Wl[c * 40 + seg * 8] =
                *(const uint4*)(w1l + (size_t)c * 128 + ch * 32 + seg * 8);
        }
        __syncthreads();
        bf16x8 afh[2], afl[2];
#pragma unroll
        for (int rt = 0; rt < 2; ++rt) {
            afh[rt] = *(bf16x8*)&Ah[(rbase + rt * 16 + l16) * 40 + quad * 8];
            afl[rt] = *(bf16x8*)&Al[(rbase + rt * 16 + l16) * 40 + quad * 8];
        }
#pragma unroll
        for (int ct = 0; ct < 2; ++ct) {
            bf16x8 bh = *(bf16x8*)&Wh[(cbase + ct * 16 + l16) * 40 + quad * 8];
            bf16x8 bl = *(bf16x8*)&Wl[(cbase + ct * 16 + l16) * 40 + quad * 8];
#pragma unroll
            for (int rt = 0; rt < 2; ++rt) {
                acc[rt][ct] = __builtin_amdgcn_mfma_f32_16x16x32_bf16(afh[rt], bh, acc[rt][ct], 0, 0, 0);
                acc[rt][ct] = __builtin_amdgcn_mfma_f32_16x16x32_bf16(afl[rt], bh, acc[rt][ct], 0, 0, 0);
                acc[rt][ct] = __builtin_amdgcn_mfma_f32_16x16x32_bf16(afh[rt], bl, acc[rt][ct], 0, 0, 0);
            }
        }
        __syncthreads();
    }
#pragma unroll
    for (int rt = 0; rt < 2; ++rt)
#pragma unroll
        for (int ct = 0; ct < 2; ++ct)
#pragma unroll
            for (int reg = 0; reg < 4; ++reg) {
                int rloc = rbase + rt * 16 + quad * 4 + reg;
                int grow = rowBase + rloc;
                if (grow < N)
                    Gout[(size_t)grow * 128 + cbase + ct * 16 + l16] =
                        f2bf_rne(acc[rt][ct][reg]);
            }
}

// Dispatches 3,4 (512 threads): fused SHARDED aggregate + gemm.
// Phase A: 64 nodes/block, 2 nodes per wave (half-wave owns a 256B row read),
// 4 nodes per half-wave. Persistent f32x4 acc per node; SHARD LOOP OUTERMOST
// so the whole chip gathers from one ~3.2MB source shard at a time (L2-hit).
// INLOOP_SCALE=1: per-neighbor dinv from L2-resident cnt4 (layer 1 rows
// unscaled). INLOOP_SCALE=0: rows prescaled -> pure sum.
// Phase B: split-bf16 gemm; epilogue prescales output rows by dinv[row].
template <int COLS, int INLOOP_SCALE>
__global__ __launch_bounds__(512, 4) void agg_gemm(
        const unsigned short* __restrict__ Gb,      // gather src, 128-wide rows
        const unsigned short* __restrict__ bucket,
        const int* __restrict__ cnt4, const float* __restrict__ bias,
        const short* __restrict__ wth, const short* __restrict__ wtl,
        unsigned short* __restrict__ Gout, int N) {
    constexpr int CT = (COLS == 128) ? 2 : 1;
    __shared__ short H[64 * 136];
    __shared__ short Wh[COLS * 40], Wl[COLS * 40];
    __shared__ float dinv_s[64];
    __shared__ int cnts_s[64][4];
    int t = threadIdx.x;
    int rowBase = blockIdx.x * 64;
    int wave = t >> 6, lane = t & 63;
    int half = lane >> 5, l32 = lane & 31;
    int c4 = l32 * 4;
    const unsigned short* __restrict__ Gc = Gb + c4;
    if (t < 64) {
        int r = rowBase + t;
        int4 cv = (r < N) ? *(const int4*)(cnt4 + (size_t)r * 4) : make_int4(0, 0, 0, 0);
        cnts_s[t][0] = cv.x; cnts_s[t][1] = cv.y;
        cnts_s[t][2] = cv.z; cnts_s[t][3] = cv.w;
        int deg = cv.x + cv.y + cv.z + cv.w;
        dinv_s[t] = (r < N) ? rsqrtf((float)(deg + 1)) : 0.f;
    }
    __syncthreads();

    // ---- phase A: persistent acc, shards outermost ----
    int nl0 = (wave * 2 + half) * 4;
    f32x4v accp[4];
#pragma unroll
    for (int i = 0; i < 4; ++i) {
        int node = rowBase + nl0 + i;
        accp[i] = {0.f, 0.f, 0.f, 0.f};
        if (node < N) {
            f32x4v s = unpack4(*(const uint2*)(Gc + (size_t)node * 128));  // self
            if constexpr (INLOOP_SCALE) accp[i] = s * dinv_s[nl0 + i];
            else accp[i] = s;
        }
    }
    for (int sh = 0; sh < NSHARD; ++sh) {
#pragma unroll
        for (int i = 0; i < 4; ++i) {
            int nl = nl0 + i;
            int node = rowBase + nl;
            if (node >= N) continue;
            int end = cnts_s[nl][sh];
            end = end < SCAP ? end : SCAP;
            const unsigned short* __restrict__ lst =
                bucket + (size_t)node * CAP + sh * SCAP;
            f32x4v a0 = {0.f, 0.f, 0.f, 0.f}, a1 = {0.f, 0.f, 0.f, 0.f};
            int p = 0;
            for (; p + 4 <= end; p += 4) {
                int sA = lst[p + 0], sB = lst[p + 1], sC = lst[p + 2], sD = lst[p + 3];
                uint2 uA = *(const uint2*)(Gc + (size_t)sA * 128);
                uint2 uB = *(const uint2*)(Gc + (size_t)sB * 128);
                uint2 uC = *(const uint2*)(Gc + (size_t)sC * 128);
                uint2 uD = *(const uint2*)(Gc + (size_t)sD * 128);
                if constexpr (INLOOP_SCALE) {
                    int4 cA = *(const int4*)(cnt4 + (size_t)sA * 4);
                    int4 cB = *(const int4*)(cnt4 + (size_t)sB * 4);
                    int4 cC = *(const int4*)(cnt4 + (size_t)sC * 4);
                    int4 cD = *(const int4*)(cnt4 + (size_t)sD * 4);
                    float dA = rsqrtf((float)(cA.x + cA.y + cA.z + cA.w + 1));
                    float dB = rsqrtf((float)(cB.x + cB.y + cB.z + cB.w + 1));
                    float dC = rsqrtf((float)(cC.x + cC.y + cC.z + cC.w + 1));
                    float dD = rsqrtf((float)(cD.x + cD.y + cD.z + cD.w + 1));
                    a0 += unpack4(uA) * dA; a1 += unpack4(uB) * dB;
                    a0 += unpack4(uC) * dC; a1 += unpack4(uD) * dD;
                } else {
                    a0 += unpack4(uA); a1 += unpack4(uB);
                    a0 += unpack4(uC); a1 += unpack4(uD);
                }
            }
            for (; p < end; ++p) {
                int s = lst[p];
                uint2 u = *(const uint2*)(Gc + (size_t)s * 128);
                if constexpr (INLOOP_SCALE) {
                    int4 cS = *(const int4*)(cnt4 + (size_t)s * 4);
                    float ds = rsqrtf((float)(cS.x + cS.y + cS.z + cS.w + 1));
                    a0 += unpack4(u) * ds;
                } else {
                    a0 += unpack4(u);
                }
            }
            accp[i] += a0 + a1;
        }
    }
#pragma unroll
    for (int i = 0; i < 4; ++i) {
        int nl = nl0 + i;
        int node = rowBase + nl;
        if (node < N) {
            float dvn = dinv_s[nl];
            float4 bb = *(const float4*)(bias + c4);
            f32x4v o;
            o.x = fmaxf(dvn * accp[i].x + bb.x, 0.f);
            o.y = fmaxf(dvn * accp[i].y + bb.y, 0.f);
            o.z = fmaxf(dvn * accp[i].z + bb.z, 0.f);
            o.w = fmaxf(dvn * accp[i].w + bb.w, 0.f);
            *(uint2*)&H[nl * 136 + c4] = pack4(o);
        } else {
            *(uint2*)&H[nl * 136 + c4] = make_uint2(0u, 0u);
        }
    }
    __syncthreads();

    // ---- phase B: 8 waves, 64xCOLS tile ----
    int quad = lane >> 4, l16 = lane & 15;
    int rbase = (wave & 1) * 32;
    int cbase = (wave >> 1) * (CT * 16);
    f32x4v acc[2][CT];
#pragma unroll
    for (int rt = 0; rt < 2; ++rt)
#pragma unroll
        for (int ct = 0; ct < CT; ++ct) acc[rt][ct] = {0.f, 0.f, 0.f, 0.f};

    for (int ch = 0; ch < 4; ++ch) {
        if (t < COLS * 4) {
            int c = t >> 2, seg = t & 3;
            *(uint4*)&Wh[c * 40 + seg * 8] =
                *(const uint4*)(wth + (size_t)c * 128 + ch * 32 + seg * 8);
            *(uint4*)&Wl[c * 40 + seg * 8] =
                *(const uint4*)(wtl + (size_t)c * 128 + ch * 32 + seg * 8);
        }
        __syncthreads();
        bf16x8 af[2];
#pragma unroll
        for (int rt = 0; rt < 2; ++rt)
            af[rt] = *(bf16x8*)&H[(rbase + rt * 16 + l16) * 136 + ch * 32 + quad * 8];
#pragma unroll
        for (int ct = 0; ct < CT; ++ct) {
            bf16x8 bh = *(bf16x8*)&Wh[(cbase + ct * 16 + l16) * 40 + quad * 8];
            bf16x8 bl = *(bf16x8*)&Wl[(cbase + ct * 16 + l16) * 40 + quad * 8];
#pragma unroll
            for (int rt = 0; rt < 2; ++rt) {
                acc[rt][ct] = __builtin_amdgcn_mfma_f32_16x16x32_bf16(af[rt], bh, acc[rt][ct], 0, 0, 0);
                acc[rt][ct] = __builtin_amdgcn_mfma_f32_16x16x32_bf16(af[rt], bl, acc[rt][ct], 0, 0, 0);
            }
        }
        __syncthreads();
    }
    // epilogue: prescale output rows by dinv[row] for the next gather
#pragma unroll
    for (int rt = 0; rt < 2; ++rt)
#pragma unroll
        for (int ct = 0; ct < CT; ++ct)
#pragma unroll
            for (int reg = 0; reg < 4; ++reg) {
                int rloc = rbase + rt * 16 + quad * 4 + reg;
                int grow = rowBase + rloc;
                if (grow < N)
                    Gout[(size_t)grow * COLS + cbase + ct * 16 + l16] =
                        f2bf_rne(dinv_s[rloc] * acc[rt][ct][reg]);
            }
}

// Dispatch 5: layer-3 aggregate (64-wide rows, PRESCALED, sharded bucket) +
// pooling. One wave per node, 4 nodes per block, block LDS reduce,
// partitioned atomics.
__global__ __launch_bounds__(256) void agg64_pool(
        const unsigned short* __restrict__ Gb,
        const unsigned short* __restrict__ bucket,
        const int* __restrict__ cnt4,
        const float* __restrict__ bias,
        const int* __restrict__ batch,
        float* __restrict__ pp, int N) {
    __shared__ float red[4][64];
    __shared__ int gg[4];
    int t = threadIdx.x;
    int wave = t >> 6, lane = t & 63;
    int node = blockIdx.x * 4 + wave;
    bool ok = node < N;
    int q = lane >> 4, l16 = lane & 15;
    int c = l16 * 4;
    const unsigned short* __restrict__ Gc = Gb + c;
    int4 cv = ok ? *(const int4*)(cnt4 + (size_t)node * 4) : make_int4(0, 0, 0, 0);
    int deg = cv.x + cv.y + cv.z + cv.w;
    float dvn = rsqrtf((float)(deg + 1));
    f32x4v acc0 = {0.f, 0.f, 0.f, 0.f}, acc1 = {0.f, 0.f, 0.f, 0.f};
    if (ok && q == 0)
        acc0 = unpack4(*(const uint2*)(Gc + (size_t)node * 64));  // self (prescaled)
    int ce[4] = {cv.x, cv.y, cv.z, cv.w};
#pragma unroll
    for (int sh = 0; sh < NSHARD; ++sh) {
        int end = ce[sh] < SCAP ? ce[sh] : SCAP;
        if (!ok) end = 0;
        const unsigned short* __restrict__ lst =
            bucket + (size_t)node * CAP + sh * SCAP;
        int p = 0;
        for (; p + 4 <= end; p += 4) {
            int s = lst[p + q];
            acc0 += unpack4(*(const uint2*)(Gc + (size_t)s * 64));
        }
        int r = end - p;
        if (q < r) {
            int s = lst[p + q];
            acc1 += unpack4(*(const uint2*)(Gc + (size_t)s * 64));
        }
    }
    f32x4v tot = acc0 + acc1;
#pragma unroll
    for (int i = 0; i < 4; ++i) {
        tot[i] += __shfl_xor(tot[i], 16, 64);
        tot[i] += __shfl_xor(tot[i], 32, 64);
    }
    if (q == 0) {
        f32x4v o = {0.f, 0.f, 0.f, 0.f};
        if (ok) {
            float4 b = *(const float4*)(bias + c);
            o.x = fmaxf(dvn * tot.x + b.x, 0.f);
            o.y = fmaxf(dvn * tot.y + b.y, 0.f);
            o.z = fmaxf(dvn * tot.z + b.z, 0.f);
            o.w = fmaxf(dvn * tot.w + b.w, 0.f);
        }
        *(f32x4v*)&red[wave][c] = o;
        if (l16 == 0) gg[wave] = ok ? batch[node] : -1;
    }
    __syncthreads();
    float* base = pp + (size_t)(blockIdx.x & (NPART - 1)) * 4096;
    if (t < 64) {
        int g0 = gg[0];
        if (g0 >= 0 && gg[1] == g0 && gg[2] == g0 && gg[3] == g0) {
            atomicAdd(base + g0 * 64 + t,
                      red[0][t] + red[1][t] + red[2][t] + red[3][t]);
        } else {
#pragma unroll
            for (int w = 0; w < 4; ++w)
                if (gg[w] >= 0) atomicAdd(base + gg[w] * 64 + t, red[w][t]);
        }
    }
}

// Dispatch 6: fold 64 partitions, divide by gcount, FC head -> out.
__global__ __launch_bounds__(256) void pool_head4(
        const float* __restrict__ pp, const int* __restrict__ gcount,
        const float* __restrict__ Wf1, const float* __restrict__ bf1,
        const float* __restrict__ Wf2, const float* __restrict__ bf2,
        float* __restrict__ out) {
    __shared__ float wf1[64 * 32];
    __shared__ float wf2[32 * 10];
    __shared__ float red[256];
    __shared__ float pl[64];
    __shared__ float f1[32];
    int g = blockIdx.x;
    int t = threadIdx.x;
    for (int i = t; i < 64 * 32; i += 256) wf1[i] = Wf1[i];
    for (int i = t; i < 32 * 10; i += 256) wf2[i] = Wf2[i];
    int f = t & 63, grp = t >> 6;
    float s = 0.f;
    for (int part = grp; part < NPART; part += 4)
        s += pp[(size_t)part * 4096 + g * 64 + f];
    red[t] = s;
    __syncthreads();
    if (t < 64)
        pl[t] = (red[t] + red[t + 64] + red[t + 128] + red[t + 192]) /
                fmaxf((float)gcount[g], 1.0f);
    __syncthreads();
    if (t < 32) {
        float v = bf1[t];
        for (int k = 0; k < 64; k++) v += pl[k] * wf1[k * 32 + t];
        f1[t] = fmaxf(v, 0.f);
    }
    __syncthreads();
    if (t < 10) {
        float v = bf2[t];
        for (int k = 0; k < 32; k++) v += f1[k] * wf2[k * 10 + t];
        out[g * 10 + t] = v;
    }
}

extern "C" void kernel_launch(void* const* d_in, const int* in_sizes, int n_in,
                              void* d_out, int out_size, void* d_ws, size_t ws_size,
                              hipStream_t stream) {
    const float* x    = (const float*)d_in[0];
    const int*   ei   = (const int*)d_in[1];   // [2,E] flat: [0..E)=src, [E..2E)=dst
    const int*   batch= (const int*)d_in[2];
    const float* W1 = (const float*)d_in[3];
    const float* b1 = (const float*)d_in[4];
    const float* W2 = (const float*)d_in[5];
    const float* b2 = (const float*)d_in[6];
    const float* W3 = (const float*)d_in[7];
    const float* b3 = (const float*)d_in[8];
    const float* Wf1 = (const float*)d_in[9];
    const float* bf1 = (const float*)d_in[10];
    const float* Wf2 = (const float*)d_in[11];
    const float* bf2 = (const float*)d_in[12];

    const int N = in_sizes[0] / 128;   // 50000 < 65536: uint16 bucket valid
    const int E = in_sizes[1] / 2;
    const int shardW = (N + NSHARD - 1) / NSHARD;

    // workspace layout
    char* w = (char*)d_ws;
    int*   cnt4  = (int*)w;   w += align256((size_t)N * 4 * 4);
    unsigned short* bucket = (unsigned short*)w; w += align256((size_t)N * CAP * 2);
    float* pp    = (float*)w; w += align256((size_t)NPART * 64 * 64 * 4);
    int*   gcount= (int*)w;   w += align256(64 * 4);
    short* w1h = (short*)w;   w += align256(16384 * 2);
    short* w1l = (short*)w;   w += align256(16384 * 2);
    short* w2h = (short*)w;   w += align256(16384 * 2);
    short* w2l = (short*)w;   w += align256(16384 * 2);
    short* w3h = (short*)w;   w += align256(8192 * 2);
    short* w3l = (short*)w;   w += align256(8192 * 2);
    unsigned short* bufA = (unsigned short*)w; w += align256((size_t)N * 128 * 2);
    unsigned short* bufB = (unsigned short*)w; w += align256((size_t)N * 128 * 2);
    unsigned short* bufC = (unsigned short*)w; w += align256((size_t)N * 64 * 2);
    (void)ws_size; (void)n_in; (void)out_size;

    (void)hipMemsetAsync(cnt4, 0, (size_t)N * 16, stream);

    int ppb = (NPART * 64 * 64) / 512;  // 512 blocks zero pp
    prep_small<<<ppb + 81, 512, 0, stream>>>(
        W1, W2, W3, w1h, w1l, w2h, w2l, w3h, w3l, pp, batch, gcount, N, ppb);

    int eb = (E + 2047) / 2048;
    int gblocks = (N + 63) / 64;
    fill_gemm1<<<eb + gblocks, 512, 0, stream>>>(
        ei, ei + E, E, eb, cnt4, bucket, x, w1h, w1l, bufA, N, shardW);

    agg_gemm<128, 1><<<gblocks, 512, 0, stream>>>(bufA, bucket, cnt4, b1,
                                                  w2h, w2l, bufB, N);
    agg_gemm<64, 0><<<gblocks, 512, 0, stream>>>(bufB, bucket, cnt4, b2,
                                                 w3h, w3l, bufC, N);

    int poolb = (N + 3) / 4;
    agg64_pool<<<poolb, 256, 0, stream>>>(bufC, bucket, cnt4, b3, batch, pp, N);

    pool_head4<<<64, 256, 0, stream>>>(pp, gcount, Wf1, bf1, Wf2, bf2,
                                       (float*)d_out);
}

// Round 8
// 236.254 us; speedup vs baseline: 1.4163x; 1.4163x over previous
//
#include <hip/hip_runtime.h>

// GCN forward on MI355X — R22: REVERT to R20 (best verified: 235.2us).
// R21 (4-way sharded gather) REFUTED the cache-blocking hypothesis:
//   agg_gemm 43.6 -> 86us, FETCH 64.5 -> 59.2MB (unchanged).
//   Mechanism: mean degree 12 -> ~3 neighbors/(node,shard) cell collapsed
//   the 4-deep gather ILP into the serial remainder path; no lockstep.
//   Conclusion: ~27G random L2 line-ops/s is a REQUEST-RATE wall, confirmed
//   across gather-128B / gather-256B / atomic-RMW / scatter and working sets
//   6.4-12.8MB. Locality tricks cannot beat it; only op-count reduction
//   could (fp8 messages = absmax gamble ~1e-3, rejected).
// Structural accounting at R20:
//   fill 1.2M + agg128 1.2M + agg64 1.2M + pool 0.6M = 4.2M ops ~ 155us
//   + ~15us serial non-wall (prep, gemm1 tail, head, memset)
//   + ~45-65us harness re-poison tax inside the window  => ~235us.
//   5 dispatches + 1 memset:
//     0. memset cnt
//     1. prep_small: W1/W2/W3 split || zero pp || gcount   (~3us)
//     2. fill_gemm1: edge fill (4/thread) || layer-1 gemm  (~49us)
//     3. agg_gemm<128,1>: gather bufA (inloop dinv) -> gemm W2 -> bufB
//     4. agg_gemm<64,0>:  gather bufB (presum) -> gemm W3 -> bufC
//     5. agg64_pool: gather bufC (presum) -> block reduce -> part. atomics
//     6. pool_head4: fold partitions + FC head
// History: R14 258.6. R15 462. R16 277.8. R18 244.8. R19 242.8. R20 235.2.
// R21 334.6 (sharding refuted).

#define CAP 64   // bucket slots per node (uint16 -> 128 B = 1 line per node)
#define NPART 64 // pooled accumulator partitions

typedef short bf16x8 __attribute__((ext_vector_type(8)));
typedef float f32x4v __attribute__((ext_vector_type(4)));

static inline size_t align256(size_t x) { return (x + 255) & ~(size_t)255; }

__device__ inline unsigned short f2bf_rne(float a) {
    unsigned u = __builtin_bit_cast(unsigned, a);
    u += 0x7fffu + ((u >> 16) & 1u);
    return (unsigned short)(u >> 16);
}
__device__ inline float bf2f(unsigned short h) {
    unsigned u = ((unsigned)h) << 16;
    return __builtin_bit_cast(float, u);
}
__device__ inline f32x4v unpack4(uint2 u) {
    f32x4v r;
    r.x = __builtin_bit_cast(float, u.x << 16);
    r.y = __builtin_bit_cast(float, u.x & 0xffff0000u);
    r.z = __builtin_bit_cast(float, u.y << 16);
    r.w = __builtin_bit_cast(float, u.y & 0xffff0000u);
    return r;
}
__device__ inline uint2 pack4(f32x4v v) {
    uint2 p;
    p.x = (unsigned)f2bf_rne(v.x) | ((unsigned)f2bf_rne(v.y) << 16);
    p.y = (unsigned)f2bf_rne(v.z) | ((unsigned)f2bf_rne(v.w) << 16);
    return p;
}

__device__ inline int lower_bound_i(const int* __restrict__ a, int n, int key) {
    int lo = 0, hi = n;
    while (lo < hi) {
        int mid = (lo + hi) >> 1;
        if (a[mid] < key) lo = mid + 1; else hi = mid;
    }
    return lo;
}

// Dispatch 1 (512 threads): [0,ppb) zero pp; [ppb,ppb+80) W1/W2/W3 split;
// last block computes gcount via binary search on sorted batch.
__global__ __launch_bounds__(512, 4) void prep_small(
        const float* __restrict__ W1, const float* __restrict__ W2,
        const float* __restrict__ W3,
        short* __restrict__ w1h, short* __restrict__ w1l,
        short* __restrict__ w2h, short* __restrict__ w2l,
        short* __restrict__ w3h, short* __restrict__ w3l,
        float* __restrict__ pp, const int* __restrict__ batch,
        int* __restrict__ gcount, int N, int ppb) {
    int b = blockIdx.x;
    int t = threadIdx.x;
    if (b < ppb) {
        pp[b * 512 + t] = 0.f;
        return;
    }
    b -= ppb;
    if (b < 80) {
        const float* W;
        short *wh, *wl;
        int idx, cols;
        if (b < 32)      { W = W1; wh = w1h; wl = w1l; idx = b * 512 + t; cols = 128; }
        else if (b < 64) { W = W2; wh = w2h; wl = w2l; idx = (b - 32) * 512 + t; cols = 128; }
        else             { W = W3; wh = w3h; wl = w3l; idx = (b - 64) * 512 + t; cols = 64; }
        int k = idx / cols, c = idx % cols;
        float a = W[idx];
        unsigned short h = f2bf_rne(a);
        unsigned short l = f2bf_rne(a - bf2f(h));
        wh[c * 128 + k] = (short)h;
        wl[c * 128 + k] = (short)l;
        return;
    }
    if (t < 64) {
        int lo = lower_bound_i(batch, N, t);
        int hi = lower_bound_i(batch, N, t + 1);
        gcount[t] = hi - lo;
    }
}

// Dispatch 2 (512 threads): [0,eb) edge fill (4 independent chains/thread);
// [eb,...) layer-1 gemm co-resident under the fill's latency.
// fp32 X, 3-product split-bf16 MFMA, UNSCALED bf16 out (dinv in agg128).
__global__ __launch_bounds__(512, 4) void fill_gemm1(
        const int* __restrict__ src, const int* __restrict__ dst, int E, int eb,
        int* __restrict__ cnt, unsigned short* __restrict__ bucket,
        const float* __restrict__ X, const short* __restrict__ w1h,
        const short* __restrict__ w1l, unsigned short* __restrict__ Gout, int N) {
    int b = blockIdx.x;
    int t = threadIdx.x;
    if (b < eb) {
        int base = b * 2048;
#pragma unroll
        for (int k = 0; k < 4; ++k) {
            int e = base + k * 512 + t;
            if (e < E) {
                int c = dst[e];
                int s = src[e];
                int p = atomicAdd(&cnt[c], 1);
                if (p < CAP) bucket[(size_t)c * CAP + p] = (unsigned short)s;
            }
        }
        return;
    }
    b -= eb;
    // ---- layer-1 gemm: 8 waves, 64x128 tile, CT=2 per wave ----
    __shared__ short Ah[64 * 40], Al[64 * 40];
    __shared__ short Wh[128 * 40], Wl[128 * 40];
    int rowBase = b * 64;
    int wave = t >> 6, lane = t & 63;
    int quad = lane >> 4, l16 = lane & 15;
    int rbase = (wave & 1) * 32;
    int cbase = (wave >> 1) * 32;
    f32x4v acc[2][2];
#pragma unroll
    for (int rt = 0; rt < 2; ++rt)
#pragma unroll
        for (int ct = 0; ct < 2; ++ct) acc[rt][ct] = {0.f, 0.f, 0.f, 0.f};

    for (int ch = 0; ch < 4; ++ch) {
        {
            int r = t >> 3, f4 = t & 7;  // 512 items, one per thread
            int grow = rowBase + r;
            float4 v = make_float4(0.f, 0.f, 0.f, 0.f);
            if (grow < N) v = *(const float4*)(X + (size_t)grow * 128 + ch * 32 + f4 * 4);
            unsigned short h0 = f2bf_rne(v.x), h1 = f2bf_rne(v.y),
                           h2 = f2bf_rne(v.z), h3 = f2bf_rne(v.w);
            unsigned short l0 = f2bf_rne(v.x - bf2f(h0)), l1 = f2bf_rne(v.y - bf2f(h1)),
                           l2 = f2bf_rne(v.z - bf2f(h2)), l3 = f2bf_rne(v.w - bf2f(h3));
            uint2 hp, lp;
            hp.x = (unsigned)h0 | ((unsigned)h1 << 16);
            hp.y = (unsigned)h2 | ((unsigned)h3 << 16);
            lp.x = (unsigned)l0 | ((unsigned)l1 << 16);
            lp.y = (unsigned)l2 | ((unsigned)l3 << 16);
            *(uint2*)&Ah[r * 40 + f4 * 4] = hp;
            *(uint2*)&Al[r * 40 + f4 * 4] = lp;
        }
        {
            int c = t >> 2, seg = t & 3;  // 512 items, one per thread
            *(uint4*)&Wh[c * 40 + seg * 8] =
                *(const uint4*)(w1h + (size_t)c * 128 + ch * 32 + seg * 8);
            *(uint4*)&Wl[c * 40 + seg * 8] =
                *(const uint4*)(w1l + (size_t)c * 128 + ch * 32 + seg * 8);
        }
        __syncthreads();
        bf16x8 afh[2], afl[2];
#pragma unroll
        for (int rt = 0; rt < 2; ++rt) {
            afh[rt] = *(bf16x8*)&Ah[(rbase + rt * 16 + l16) * 40 + quad * 8];
            afl[rt] = *(bf16x8*)&Al[(rbase + rt * 16 + l16) * 40 + quad * 8];
        }
#pragma unroll
        for (int ct = 0; ct < 2; ++ct) {
            bf16x8 bh = *(bf16x8*)&Wh[(cbase + ct * 16 + l16) * 40 + quad * 8];
            bf16x8 bl = *(bf16x8*)&Wl[(cbase + ct * 16 + l16) * 40 + quad * 8];
#pragma unroll
            for (int rt = 0; rt < 2; ++rt) {
                acc[rt][ct] = __builtin_amdgcn_mfma_f32_16x16x32_bf16(afh[rt], bh, acc[rt][ct], 0, 0, 0);
                acc[rt][ct] = __builtin_amdgcn_mfma_f32_16x16x32_bf16(afl[rt], bh, acc[rt][ct], 0, 0, 0);
                acc[rt][ct] = __builtin_amdgcn_mfma_f32_16x16x32_bf16(afh[rt], bl, acc[rt][ct], 0, 0, 0);
            }
        }
        __syncthreads();
    }
#pragma unroll
    for (int rt = 0; rt < 2; ++rt)
#pragma unroll
        for (int ct = 0; ct < 2; ++ct)
#pragma unroll
            for (int reg = 0; reg < 4; ++reg) {
                int rloc = rbase + rt * 16 + quad * 4 + reg;
                int grow = rowBase + rloc;
                if (grow < N)
                    Gout[(size_t)grow * 128 + cbase + ct * 16 + l16] =
                        f2bf_rne(acc[rt][ct][reg]);
            }
}

// Dispatches 3,4 (512 threads): fused aggregate + gemm.
// Phase A: 64 nodes/block, 2 nodes per wave concurrently (half-wave owns a
// full 256B row read), 4 nodes per half-wave serially. INLOOP_SCALE=1:
// gather rows are unscaled -> apply dinv[src] per row (layer 1).
// INLOOP_SCALE=0: rows prescaled -> pure sum. relu+bias -> bf16 H[64][136].
// Phase B: split-bf16 gemm (8 waves, CT tiles), epilogue scales by dinv[row]
// so the OUTPUT rows are prescaled for the next gather.
template <int COLS, int INLOOP_SCALE>
__global__ __launch_bounds__(512, 4) void agg_gemm(
        const unsigned short* __restrict__ Gb,      // gather src, 128-wide rows
        const unsigned short* __restrict__ bucket,
        const int* __restrict__ cnt, const float* __restrict__ bias,
        const short* __restrict__ wth, const short* __restrict__ wtl,
        unsigned short* __restrict__ Gout, int N) {
    constexpr int CT = (COLS == 128) ? 2 : 1;
    __shared__ short H[64 * 136];
    __shared__ short Wh[COLS * 40], Wl[COLS * 40];
    __shared__ float dinv_s[64];
    int t = threadIdx.x;
    int rowBase = blockIdx.x * 64;
    int wave = t >> 6, lane = t & 63;
    int half = lane >> 5, l32 = lane & 31;
    int c4 = l32 * 4;
    const unsigned short* __restrict__ Gc = Gb + c4;
    if (t < 64) {
        int r = rowBase + t;
        dinv_s[t] = (r < N) ? rsqrtf((float)(cnt[r] + 1)) : 0.f;
    }
    __syncthreads();

    // ---- phase A: 4 nodes per half-wave ----
    for (int i = 0; i < 4; ++i) {
        int nl = (wave * 2 + half) * 4 + i;
        int node = rowBase + nl;
        bool ok = node < N;
        float dvn = dinv_s[nl];
        int deg = ok ? cnt[node] : 0;
        int end = ok ? (deg < CAP ? deg : CAP) : 0;
        const unsigned short* __restrict__ lst = bucket + (size_t)node * CAP;
        f32x4v a0 = {0.f, 0.f, 0.f, 0.f}, a1 = {0.f, 0.f, 0.f, 0.f};
        if (ok) {
            f32x4v s = unpack4(*(const uint2*)(Gc + (size_t)node * 128));  // self
            if constexpr (INLOOP_SCALE) a0 = s * dvn; else a0 = s;
        }
        int p = 0;
        for (; p + 4 <= end; p += 4) {
            int sA = lst[p + 0], sB = lst[p + 1], sC = lst[p + 2], sD = lst[p + 3];
            uint2 uA = *(const uint2*)(Gc + (size_t)sA * 128);
            uint2 uB = *(const uint2*)(Gc + (size_t)sB * 128);
            uint2 uC = *(const uint2*)(Gc + (size_t)sC * 128);
            uint2 uD = *(const uint2*)(Gc + (size_t)sD * 128);
            if constexpr (INLOOP_SCALE) {
                float dA = rsqrtf((float)(cnt[sA] + 1));
                float dB = rsqrtf((float)(cnt[sB] + 1));
                float dC = rsqrtf((float)(cnt[sC] + 1));
                float dD = rsqrtf((float)(cnt[sD] + 1));
                a0 += unpack4(uA) * dA; a1 += unpack4(uB) * dB;
                a0 += unpack4(uC) * dC; a1 += unpack4(uD) * dD;
            } else {
                a0 += unpack4(uA); a1 += unpack4(uB);
                a0 += unpack4(uC); a1 += unpack4(uD);
            }
        }
        for (; p < end; ++p) {
            int s = lst[p];
            uint2 u = *(const uint2*)(Gc + (size_t)s * 128);
            if constexpr (INLOOP_SCALE) {
                float ds = rsqrtf((float)(cnt[s] + 1));
                a0 += unpack4(u) * ds;
            } else {
                a0 += unpack4(u);
            }
        }
        f32x4v tot = a0 + a1;
        if (ok) {
            float4 bb = *(const float4*)(bias + c4);
            f32x4v o;
            o.x = fmaxf(dvn * tot.x + bb.x, 0.f);
            o.y = fmaxf(dvn * tot.y + bb.y, 0.f);
            o.z = fmaxf(dvn * tot.z + bb.z, 0.f);
            o.w = fmaxf(dvn * tot.w + bb.w, 0.f);
            *(uint2*)&H[nl * 136 + c4] = pack4(o);
        } else {
            *(uint2*)&H[nl * 136 + c4] = make_uint2(0u, 0u);
        }
    }
    __syncthreads();

    // ---- phase B: 8 waves, 64xCOLS tile ----
    int quad = lane >> 4, l16 = lane & 15;
    int rbase = (wave & 1) * 32;
    int cbase = (wave >> 1) * (CT * 16);
    f32x4v acc[2][CT];
#pragma unroll
    for (int rt = 0; rt < 2; ++rt)
#pragma unroll
        for (int ct = 0; ct < CT; ++ct) acc[rt][ct] = {0.f, 0.f, 0.f, 0.f};

    for (int ch = 0; ch < 4; ++ch) {
        if (t < COLS * 4) {
            int c = t >> 2, seg = t & 3;
            *(uint4*)&Wh[c * 40 + seg * 8] =
                *(const uint4*)(wth + (size_t)c * 128 + ch * 32 + seg * 8);
            *(uint4*)&Wl[c * 40 + seg * 8] =
                *(const uint4*)(wtl + (size_t)c * 128 + ch * 32 + seg * 8);
        }
        __syncthreads();
        bf16x8 af[2];
#pragma unroll
        for (int rt = 0; rt < 2; ++rt)
            af[rt] = *(bf16x8*)&H[(rbase + rt * 16 + l16) * 136 + ch * 32 + quad * 8];
#pragma unroll
        for (int ct = 0; ct < CT; ++ct) {
            bf16x8 bh = *(bf16x8*)&Wh[(cbase + ct * 16 + l16) * 40 + quad * 8];
            bf16x8 bl = *(bf16x8*)&Wl[(cbase + ct * 16 + l16) * 40 + quad * 8];
#pragma unroll
            for (int rt = 0; rt < 2; ++rt) {
                acc[rt][ct] = __builtin_amdgcn_mfma_f32_16x16x32_bf16(af[rt], bh, acc[rt][ct], 0, 0, 0);
                acc[rt][ct] = __builtin_amdgcn_mfma_f32_16x16x32_bf16(af[rt], bl, acc[rt][ct], 0, 0, 0);
            }
        }
        __syncthreads();
    }
    // epilogue: prescale output rows by dinv[row] for the next gather
#pragma unroll
    for (int rt = 0; rt < 2; ++rt)
#pragma unroll
        for (int ct = 0; ct < CT; ++ct)
#pragma unroll
            for (int reg = 0; reg < 4; ++reg) {
                int rloc = rbase + rt * 16 + quad * 4 + reg;
                int grow = rowBase + rloc;
                if (grow < N)
                    Gout[(size_t)grow * COLS + cbase + ct * 16 + l16] =
                        f2bf_rne(dinv_s[rloc] * acc[rt][ct][reg]);
            }
}

// Dispatch 5: layer-3 aggregate (64-wide rows, PRESCALED) + pooling.
// One wave per node, 4 nodes per block, block LDS reduce, partitioned atomics.
__global__ __launch_bounds__(256) void agg64_pool(
        const unsigned short* __restrict__ Gb,
        const unsigned short* __restrict__ bucket,
        const int* __restrict__ cnt,
        const float* __restrict__ bias,
        const int* __restrict__ batch,
        float* __restrict__ pp, int N) {
    __shared__ float red[4][64];
    __shared__ int gg[4];
    int t = threadIdx.x;
    int wave = t >> 6, lane = t & 63;
    int node = blockIdx.x * 4 + wave;
    bool ok = node < N;
    int q = lane >> 4, l16 = lane & 15;
    int c = l16 * 4;
    const unsigned short* __restrict__ Gc = Gb + c;
    int deg = ok ? cnt[node] : 0;
    float dvn = rsqrtf((float)(deg + 1));
    int end = ok ? (deg < CAP ? deg : CAP) : 0;
    const unsigned short* __restrict__ lst = bucket + (size_t)node * CAP;
    f32x4v acc0 = {0.f, 0.f, 0.f, 0.f}, acc1 = {0.f, 0.f, 0.f, 0.f};
    if (ok && q == 0)
        acc0 = unpack4(*(const uint2*)(Gc + (size_t)node * 64));  // self (prescaled)
    int p = 0;
    for (; p + 8 <= end; p += 8) {
        int sA = lst[p + q];
        int sB = lst[p + 4 + q];
        uint2 uA = *(const uint2*)(Gc + (size_t)sA * 64);
        uint2 uB = *(const uint2*)(Gc + (size_t)sB * 64);
        acc0 += unpack4(uA);
        acc1 += unpack4(uB);
    }
    for (; p + 4 <= end; p += 4) {
        int s = lst[p + q];
        acc0 += unpack4(*(const uint2*)(Gc + (size_t)s * 64));
    }
    int r = end - p;
    if (r > 0) {
        int s = (q < r) ? (int)lst[p + q] : node;
        uint2 u = *(const uint2*)(Gc + (size_t)s * 64);
        if (q < r) acc0 += unpack4(u);
    }
    f32x4v tot = acc0 + acc1;
#pragma unroll
    for (int i = 0; i < 4; ++i) {
        tot[i] += __shfl_xor(tot[i], 16, 64);
        tot[i] += __shfl_xor(tot[i], 32, 64);
    }
    if (q == 0) {
        f32x4v o = {0.f, 0.f, 0.f, 0.f};
        if (ok) {
            float4 b = *(const float4*)(bias + c);
            o.x = fmaxf(dvn * tot.x + b.x, 0.f);
            o.y = fmaxf(dvn * tot.y + b.y, 0.f);
            o.z = fmaxf(dvn * tot.z + b.z, 0.f);
            o.w = fmaxf(dvn * tot.w + b.w, 0.f);
        }
        *(f32x4v*)&red[wave][c] = o;
        if (l16 == 0) gg[wave] = ok ? batch[node] : -1;
    }
    __syncthreads();
    float* base = pp + (size_t)(blockIdx.x & (NPART - 1)) * 4096;
    if (t < 64) {
        int g0 = gg[0];
        if (g0 >= 0 && gg[1] == g0 && gg[2] == g0 && gg[3] == g0) {
            atomicAdd(base + g0 * 64 + t,
                      red[0][t] + red[1][t] + red[2][t] + red[3][t]);
        } else {
#pragma unroll
            for (int w = 0; w < 4; ++w)
                if (gg[w] >= 0) atomicAdd(base + gg[w] * 64 + t, red[w][t]);
        }
    }
}

// Dispatch 6: fold 64 partitions, divide by gcount, FC head -> out.
__global__ __launch_bounds__(256) void pool_head4(
        const float* __restrict__ pp, const int* __restrict__ gcount,
        const float* __restrict__ Wf1, const float* __restrict__ bf1,
        const float* __restrict__ Wf2, const float* __restrict__ bf2,
        float* __restrict__ out) {
    __shared__ float wf1[64 * 32];
    __shared__ float wf2[32 * 10];
    __shared__ float red[256];
    __shared__ float pl[64];
    __shared__ float f1[32];
    int g = blockIdx.x;
    int t = threadIdx.x;
    for (int i = t; i < 64 * 32; i += 256) wf1[i] = Wf1[i];
    for (int i = t; i < 32 * 10; i += 256) wf2[i] = Wf2[i];
    int f = t & 63, grp = t >> 6;
    float s = 0.f;
    for (int part = grp; part < NPART; part += 4)
        s += pp[(size_t)part * 4096 + g * 64 + f];
    red[t] = s;
    __syncthreads();
    if (t < 64)
        pl[t] = (red[t] + red[t + 64] + red[t + 128] + red[t + 192]) /
                fmaxf((float)gcount[g], 1.0f);
    __syncthreads();
    if (t < 32) {
        float v = bf1[t];
        for (int k = 0; k < 64; k++) v += pl[k] * wf1[k * 32 + t];
        f1[t] = fmaxf(v, 0.f);
    }
    __syncthreads();
    if (t < 10) {
        float v = bf2[t];
        for (int k = 0; k < 32; k++) v += f1[k] * wf2[k * 10 + t];
        out[g * 10 + t] = v;
    }
}

extern "C" void kernel_launch(void* const* d_in, const int* in_sizes, int n_in,
                              void* d_out, int out_size, void* d_ws, size_t ws_size,
                              hipStream_t stream) {
    const float* x    = (const float*)d_in[0];
    const int*   ei   = (const int*)d_in[1];   // [2,E] flat: [0..E)=src, [E..2E)=dst
    const int*   batch= (const int*)d_in[2];
    const float* W1 = (const float*)d_in[3];
    const float* b1 = (const float*)d_in[4];
    const float* W2 = (const float*)d_in[5];
    const float* b2 = (const float*)d_in[6];
    const float* W3 = (const float*)d_in[7];
    const float* b3 = (const float*)d_in[8];
    const float* Wf1 = (const float*)d_in[9];
    const float* bf1 = (const float*)d_in[10];
    const float* Wf2 = (const float*)d_in[11];
    const float* bf2 = (const float*)d_in[12];

    const int N = in_sizes[0] / 128;   // 50000 < 65536: uint16 bucket valid
    const int E = in_sizes[1] / 2;

    // workspace layout
    char* w = (char*)d_ws;
    int*   cnt   = (int*)w;   w += align256((size_t)N * 4);
    unsigned short* bucket = (unsigned short*)w; w += align256((size_t)N * CAP * 2);
    float* pp    = (float*)w; w += align256((size_t)NPART * 64 * 64 * 4);
    int*   gcount= (int*)w;   w += align256(64 * 4);
    short* w1h = (short*)w;   w += align256(16384 * 2);
    short* w1l = (short*)w;   w += align256(16384 * 2);
    short* w2h = (short*)w;   w += align256(16384 * 2);
    short* w2l = (short*)w;   w += align256(16384 * 2);
    short* w3h = (short*)w;   w += align256(8192 * 2);
    short* w3l = (short*)w;   w += align256(8192 * 2);
    unsigned short* bufA = (unsigned short*)w; w += align256((size_t)N * 128 * 2);
    unsigned short* bufB = (unsigned short*)w; w += align256((size_t)N * 128 * 2);
    unsigned short* bufC = (unsigned short*)w; w += align256((size_t)N * 64 * 2);
    (void)ws_size; (void)n_in; (void)out_size;

    (void)hipMemsetAsync(cnt, 0, (size_t)N * 4, stream);

    int ppb = (NPART * 64 * 64) / 512;  // 512 blocks zero pp
    prep_small<<<ppb + 81, 512, 0, stream>>>(
        W1, W2, W3, w1h, w1l, w2h, w2l, w3h, w3l, pp, batch, gcount, N, ppb);

    int eb = (E + 2047) / 2048;
    int gblocks = (N + 63) / 64;
    fill_gemm1<<<eb + gblocks, 512, 0, stream>>>(
        ei, ei + E, E, eb, cnt, bucket, x, w1h, w1l, bufA, N);

    agg_gemm<128, 1><<<gblocks, 512, 0, stream>>>(bufA, bucket, cnt, b1,
                                                  w2h, w2l, bufB, N);
    agg_gemm<64, 0><<<gblocks, 512, 0, stream>>>(bufB, bucket, cnt, b2,
                                                 w3h, w3l, bufC, N);

    int poolb = (N + 3) / 4;
    agg64_pool<<<poolb, 256, 0, stream>>>(bufC, bucket, cnt, b3, batch, pp, N);

    pool_head4<<<64, 256, 0, stream>>>(pp, gcount, Wf1, bf1, Wf2, bf2,
                                       (float*)d_out);
}